// Round 3
// baseline (57.386 us; speedup 1.0000x reference)
//
#include <hip/hip_runtime.h>
#include <stdint.h>

// SWF2LUT 4-simplex interpolation, mode 's'.
// img_in: (8,1,513,513) f32, integer values 0..255
// weight: (17^4, 3) f32  -> quantized clip(round(w*127),-127,127)
// out:    (8,1,512,512,3) f32
//
// Round-3 layout: the L1 cost of divergent gathers is per-INSTRUCTION line
// serialization (64 lanes -> 64 distinct lines -> ~64 cy/instr). Rounds 1-2
// issued 5 gather instrs/pixel. Here we pre-expand the LUT by simplex
// permutation: tab[perm][cell] = one 16B entry holding all 5 taps x 3
// channels as int8. Interp then does ONE dwordx4 gather per pixel.

#define LQ   17
#define L2C  (17 * 17)        // 289
#define L3C  (17 * 17 * 17)   // 4913
#define NENT (L3C * 17)       // 83521
#define NCELL 65536           // 16^4 cells
#define NPERM 24
#define SUMSTRIDE (L3C + L2C + LQ + 1)  // 5220

__device__ __forceinline__ int quant_i8(float x) {
    int q = (int)rintf(x * 127.0f);           // round-half-even == jnp.round
    return min(127, max(-127, q));
}

// sign-extend byte k (0..3) of word W
#define SX(W, k) ((int)((W) << (24 - 8 * (k))) >> 24)

// ---- pre-kernel: expand weights into [perm][cell] 16B simplex entries ----
// One thread per cell. Corners of the cell -> 24 permutation entries, each
// the 5 path taps (c0=0, c1, c2, c3, c4=15) x 3 ch packed as 15 int8 + pad.
__global__ __launch_bounds__(256) void build_perm_kernel(
    const float* __restrict__ w, uint4* __restrict__ tab) {
    int cell = blockIdx.x * 256 + threadIdx.x;      // 0..65535
    int ia = (cell >> 12) & 15, ib = (cell >> 8) & 15;
    int ic = (cell >> 4) & 15,  id = cell & 15;
    int base = ia * L3C + ib * L2C + ic * LQ + id;
    uint32_t cr[16];
#pragma unroll
    for (int c = 0; c < 16; ++c) {
        // corner c: bit3->a+1, bit2->b+1, bit1->c+1, bit0->d+1
        int off = ((c >> 3) & 1) * L3C + ((c >> 2) & 1) * L2C +
                  ((c >> 1) & 1) * LQ + (c & 1);
        const float* p = w + (size_t)(base + off) * 3;
        int q0 = quant_i8(p[0]);
        int q1 = quant_i8(p[1]);
        int q2 = quant_i8(p[2]);
        cr[c] = (uint32_t)(q0 & 0xFF) | ((uint32_t)(q1 & 0xFF) << 8) |
                ((uint32_t)(q2 & 0xFF) << 16);   // bits 24..31 stay 0
    }
    // enumerate the 24 axis orders by Lehmer code (l0,l1,l2); fully unrolled
#pragma unroll
    for (int l0 = 0; l0 < 4; ++l0) {
#pragma unroll
        for (int l1 = 0; l1 < 3; ++l1) {
#pragma unroll
            for (int l2 = 0; l2 < 2; ++l2) {
                int lst0 = 0, lst1 = 1, lst2 = 2, lst3 = 3;
                // a0 = lst[l0]; remove
                int a0 = (l0 == 0) ? lst0 : (l0 == 1) ? lst1
                          : (l0 == 2) ? lst2 : lst3;
                int r0 = (l0 == 0) ? lst1 : lst0;
                int r1 = (l0 <= 1) ? lst2 : lst1;
                int r2 = (l0 <= 2) ? lst3 : lst2;
                int a1 = (l1 == 0) ? r0 : (l1 == 1) ? r1 : r2;
                int s0 = (l1 == 0) ? r1 : r0;
                int s1 = (l1 <= 1) ? r2 : r1;
                int a2 = (l2 == 0) ? s0 : s1;
                // corner codes along the monotone path
                int c1 = 8 >> a0;
                int c2 = c1 | (8 >> a1);
                int c3 = c2 | (8 >> a2);
                uint32_t t0 = cr[0], t1 = cr[c1], t2 = cr[c2], t3 = cr[c3],
                         t4 = cr[15];
                uint4 u;
                u.x = t0 | (t1 << 24);
                u.y = (t1 >> 8) | (t2 << 16);
                u.z = (t2 >> 16) | (t3 << 8);
                u.w = t4;
                int perm = l0 * 6 + l1 * 2 + l2;
                tab[(size_t)perm * NCELL + cell] = u;  // lanes contiguous
            }
        }
    }
}

// ---- main kernel: one thread = 4 consecutive x pixels, 1 gather/pixel ----
__global__ __launch_bounds__(256) void interp_perm_kernel(
    const float* __restrict__ img, const uint4* __restrict__ tab,
    float* __restrict__ out) {
    int gid = blockIdx.x * 256 + threadIdx.x;   // 0..524287
    int x0 = (gid & 127) << 2;                  // 0..508 step 4
    int y  = (gid >> 7) & 511;
    int im = gid >> 16;                         // 0..7

    const float* r0 = img + im * (513 * 513) + y * 513 + x0;
    const float* r1 = r0 + 513;
    float v0[5], v1[5];
#pragma unroll
    for (int i = 0; i < 5; ++i) { v0[i] = r0[i]; v1[i] = r1[i]; }

    float res[12];
#pragma unroll
    for (int i = 0; i < 4; ++i) {
        int a = (int)v0[i], b = (int)v0[i + 1];
        int c = (int)v1[i], d = (int)v1[i + 1];
        int cell = ((a & 0xF0) << 8) | ((b & 0xF0) << 4) |
                   (c & 0xF0) | (d >> 4);
        // keys: f*4 + coord_index (distinct; replicates argsort(-tie_key))
        int k0 = ((a & 15) << 2) | 0;
        int k1 = ((b & 15) << 2) | 1;
        int k2 = ((c & 15) << 2) | 2;
        int k3 = ((d & 15) << 2) | 3;
        int t;
        if (k0 < k1) { t = k0; k0 = k1; k1 = t; }
        if (k2 < k3) { t = k2; k2 = k3; k3 = t; }
        if (k0 < k2) { t = k0; k0 = k2; k2 = t; }
        if (k1 < k3) { t = k1; k1 = k3; k3 = t; }
        if (k1 < k2) { t = k1; k1 = k2; k2 = t; }
        int fs0 = k0 >> 2, fs1 = k1 >> 2, fs2 = k2 >> 2, fs3 = k3 >> 2;
        // Lehmer encode of the axis sequence -> perm id (matches build)
        int a0 = k0 & 3, a1 = k1 & 3, a2 = k2 & 3, a3 = k3 & 3;
        int l1 = a1 - (a1 > a0 ? 1 : 0);
        int l2 = (a2 > a3) ? 1 : 0;
        int perm = a0 * 6 + l1 * 2 + l2;

        uint4 u = tab[(size_t)perm * NCELL + cell];  // ONE gather per pixel

        int w0 = 16 - fs0, w1 = fs0 - fs1, w2 = fs1 - fs2, w3 = fs2 - fs3,
            w4 = fs3;
        // byte m = tap*3 + ch
        int acc0 = w0 * SX(u.x, 0) + w1 * SX(u.x, 3) + w2 * SX(u.y, 2) +
                   w3 * SX(u.z, 1) + w4 * SX(u.w, 0);
        int acc1 = w0 * SX(u.x, 1) + w1 * SX(u.y, 0) + w2 * SX(u.y, 3) +
                   w3 * SX(u.z, 2) + w4 * SX(u.w, 1);
        int acc2 = w0 * SX(u.x, 2) + w1 * SX(u.y, 1) + w2 * SX(u.z, 0) +
                   w3 * SX(u.z, 3) + w4 * SX(u.w, 2);
        res[i * 3 + 0] = (float)acc0 * 0.0625f;  // /16 exact
        res[i * 3 + 1] = (float)acc1 * 0.0625f;
        res[i * 3 + 2] = (float)acc2 * 0.0625f;
    }

    int opix = ((im * 512 + y) * 512 + x0) * 3;  // multiple of 12 -> 48B aligned
    float4* o = (float4*)(out + opix);
    o[0] = make_float4(res[0], res[1], res[2], res[3]);
    o[1] = make_float4(res[4], res[5], res[6], res[7]);
    o[2] = make_float4(res[8], res[9], res[10], res[11]);
}

// ---- fallback: gather f32 weights, quantize inline (if ws too small) ----
__device__ __forceinline__ float quant1(float x) {
    return fminf(127.0f, fmaxf(-127.0f, rintf(x * 127.0f)));
}

__device__ __forceinline__ int stride_of(int j) {
    return j == 0 ? L3C : (j == 1 ? L2C : (j == 2 ? LQ : 1));
}

__global__ __launch_bounds__(256) void interp_float_kernel(
    const float* __restrict__ img, const float* __restrict__ wgt,
    float* __restrict__ out) {
    int gid = blockIdx.x * 256 + threadIdx.x;
    int x0 = (gid & 127) << 2;
    int y  = (gid >> 7) & 511;
    int im = gid >> 16;

    const float* r0 = img + im * (513 * 513) + y * 513 + x0;
    const float* r1 = r0 + 513;
    float v0[5], v1[5];
#pragma unroll
    for (int i = 0; i < 5; ++i) { v0[i] = r0[i]; v1[i] = r1[i]; }

    float res[12];
#pragma unroll
    for (int i = 0; i < 4; ++i) {
        int a = (int)v0[i], b = (int)v0[i + 1];
        int c = (int)v1[i], d = (int)v1[i + 1];
        int base = (a >> 4) * L3C + (b >> 4) * L2C + (c >> 4) * LQ + (d >> 4);
        int k0 = ((a & 15) << 2) | 0;
        int k1 = ((b & 15) << 2) | 1;
        int k2 = ((c & 15) << 2) | 2;
        int k3 = ((d & 15) << 2) | 3;
        int t;
        if (k0 < k1) { t = k0; k0 = k1; k1 = t; }
        if (k2 < k3) { t = k2; k2 = k3; k3 = t; }
        if (k0 < k2) { t = k0; k0 = k2; k2 = t; }
        if (k1 < k3) { t = k1; k1 = k3; k3 = t; }
        if (k1 < k2) { t = k1; k1 = k2; k2 = t; }
        int fs0 = k0 >> 2, fs1 = k1 >> 2, fs2 = k2 >> 2, fs3 = k3 >> 2;
        int s0 = stride_of(k0 & 3);
        int s1 = stride_of(k1 & 3);
        int s2 = stride_of(k2 & 3);
        int i0 = base;
        int i1 = base + s0;
        int i2 = i1 + s1;
        int i3 = i2 + s2;
        int i4 = base + SUMSTRIDE;
        float w0 = (float)(16 - fs0), w1 = (float)(fs0 - fs1),
              w2 = (float)(fs1 - fs2), w3 = (float)(fs2 - fs3),
              w4 = (float)fs3;
#pragma unroll
        for (int ch = 0; ch < 3; ++ch) {
            float p0 = quant1(wgt[i0 * 3 + ch]);
            float p1 = quant1(wgt[i1 * 3 + ch]);
            float p2 = quant1(wgt[i2 * 3 + ch]);
            float p3 = quant1(wgt[i3 * 3 + ch]);
            float p4 = quant1(wgt[i4 * 3 + ch]);
            float acc = w0 * p0 + w1 * p1 + w2 * p2 + w3 * p3 + w4 * p4;
            res[i * 3 + ch] = acc * 0.0625f;
        }
    }

    int opix = ((im * 512 + y) * 512 + x0) * 3;
    float4* o = (float4*)(out + opix);
    o[0] = make_float4(res[0], res[1], res[2], res[3]);
    o[1] = make_float4(res[4], res[5], res[6], res[7]);
    o[2] = make_float4(res[8], res[9], res[10], res[11]);
}

extern "C" void kernel_launch(void* const* d_in, const int* in_sizes, int n_in,
                              void* d_out, int out_size, void* d_ws,
                              size_t ws_size, hipStream_t stream) {
    const float* img = (const float*)d_in[0];
    const float* wgt = (const float*)d_in[1];
    float* out = (float*)d_out;

    const int n_groups = 8 * 512 * 128;      // 524288 threads, 4 px each
    const int grid = n_groups / 256;         // 2048 blocks

    const size_t tab_bytes = (size_t)NPERM * NCELL * 16;  // 24 MiB
    if (ws_size >= tab_bytes && d_ws != nullptr) {
        uint4* tab = (uint4*)d_ws;           // 16B-aligned
        build_perm_kernel<<<NCELL / 256, 256, 0, stream>>>(wgt, tab);
        interp_perm_kernel<<<grid, 256, 0, stream>>>(img, tab, out);
    } else {
        interp_float_kernel<<<grid, 256, 0, stream>>>(img, wgt, out);
    }
}